// Round 1
// baseline (188.090 us; speedup 1.0000x reference)
//
#include <hip/hip_runtime.h>

// QRNN: B=8 T=2048 C=512 U=512 W=2
// Pipeline:
//  1. conv_x:  x fp32 [B,T,C] -> xb bf16 [B,T+1,C] (row t=0 zeroed => causal pad)
//  2. conv_k:  kernel fp32 [W,C,3U]=[1024,1536] -> kT bf16 [1536,1024] (transposed, n-major)
//  3. gemm_gates: bf16 MFMA 16x16x32, tile 128x128, BK=32, global_load_lds(16B) staging.
//     A row m=(b,t) = xb + (m+b)*C  (covers x[b,t-1..t], 1024 elems, contiguous).
//     Epilogue fuses +bias and tanh/sigmoid; writes activated z|f|o fp32 [16384,1536].
//  4-6. chunked linear-recurrence scan: per-chunk (a,bv) affine, global chunk scan, replay.
// Workspace: xb 16.8MB + kT 3.1MB + gates 100.7MB + scan 1.5MB = ~117 MiB.

#define Bn 8
#define Tn 2048
#define Cn 512
#define Un 512
#define Nn 1536
#define Kn 1024
#define Mn (Bn * Tn)
#define NC 32   // chunks per sequence
#define CL 64   // chunk length (NC*CL == Tn)

using bf16x8 = __attribute__((ext_vector_type(8))) __bf16;
using f32x4  = __attribute__((ext_vector_type(4))) float;

__device__ __forceinline__ void async16(const void* g, void* l) {
  __builtin_amdgcn_global_load_lds((const __attribute__((address_space(1))) void*)g,
                                   (__attribute__((address_space(3))) void*)l, 16, 0, 0);
}

__device__ __forceinline__ unsigned short f2bf(float v) {
  union { float f; unsigned u; } c; c.f = v;
  unsigned u = c.u;
  return (unsigned short)((u + 0x7fffu + ((u >> 16) & 1u)) >> 16);  // RNE
}

__device__ __forceinline__ float fast_sigmoid(float x) {
  float e = __builtin_amdgcn_exp2f(-1.4426950408889634f * x);
  return __builtin_amdgcn_rcpf(1.0f + e);
}
__device__ __forceinline__ float fast_tanh(float x) {
  float e = __builtin_amdgcn_exp2f(-2.8853900817779268f * x);
  return 2.0f * __builtin_amdgcn_rcpf(1.0f + e) - 1.0f;
}

// ---- 1. x -> padded bf16 ----------------------------------------------------
__global__ __launch_bounds__(256) void conv_x(const float* __restrict__ x,
                                              unsigned short* __restrict__ xb) {
  int idx = blockIdx.x * 256 + threadIdx.x;   // over B*(T+1)*C/4
  int c4  = idx & 127;                        // C/4 = 128
  int row = idx >> 7;                         // b*(T+1)+t
  int b   = row / (Tn + 1);
  int t   = row - b * (Tn + 1);
  ushort4 ov;
  if (t == 0) {
    ov.x = ov.y = ov.z = ov.w = 0;
  } else {
    float4 v = *(const float4*)(x + (size_t)(b * Tn + t - 1) * Cn + c4 * 4);
    ov.x = f2bf(v.x); ov.y = f2bf(v.y); ov.z = f2bf(v.z); ov.w = f2bf(v.w);
  }
  *(ushort4*)(xb + (size_t)row * Cn + c4 * 4) = ov;
}

// ---- 2. kernel -> bf16 transposed [N][K] ------------------------------------
__global__ __launch_bounds__(256) void conv_k(const float* __restrict__ kern,
                                              unsigned short* __restrict__ kT) {
  __shared__ float tile[32][33];
  int kb = blockIdx.x, nb = blockIdx.y;       // grid (32, 48)
  int tx = threadIdx.x & 31, ty = threadIdx.x >> 5;
#pragma unroll
  for (int i = 0; i < 4; i++)
    tile[ty + i * 8][tx] = kern[(size_t)(kb * 32 + ty + i * 8) * Nn + nb * 32 + tx];
  __syncthreads();
#pragma unroll
  for (int i = 0; i < 4; i++) {
    int n = nb * 32 + ty + i * 8;
    int k = kb * 32 + tx;
    kT[(size_t)n * Kn + k] = f2bf(tile[tx][ty + i * 8]);
  }
}

// ---- 3. MFMA GEMM + activation epilogue -------------------------------------
__global__ __launch_bounds__(256) void gemm_gates(const unsigned short* __restrict__ xb,
                                                  const unsigned short* __restrict__ kT,
                                                  const float* __restrict__ bias,
                                                  float* __restrict__ gates) {
  __shared__ unsigned short As[128 * 32];   // [m][k]
  __shared__ unsigned short Bs[128 * 32];   // [n][k]  (k contiguous -> ds_read_b128 frags)
  const int tid = threadIdx.x;
  const int m0 = blockIdx.x * 128;          // 128 row tiles
  const int n0 = blockIdx.y * 128;          // 12 col tiles
  const int batch = m0 / Tn;                // tiles never cross batch (2048/128=16)
  const int lane = tid & 63;
  const int w = tid >> 6, wr = w >> 1, wc = w & 1;

  // staging sources: lane writes LDS bytes [tid*16, +16) (wave-uniform base + lane*16)
  const unsigned short* aSrc = xb + (size_t)(m0 + batch + (tid >> 2)) * Cn + (tid & 3) * 8;
  const unsigned short* bSrc = kT + (size_t)(n0 + (tid >> 2)) * Kn + (tid & 3) * 8;

  f32x4 zero = {0.f, 0.f, 0.f, 0.f};
  f32x4 acc[4][4];
#pragma unroll
  for (int i = 0; i < 4; i++)
#pragma unroll
    for (int j = 0; j < 4; j++) acc[i][j] = zero;

  for (int k0 = 0; k0 < Kn; k0 += 32) {
    async16(aSrc + k0,            &As[tid * 8]);
    async16(aSrc + 64 * Cn + k0,  &As[2048 + tid * 8]);
    async16(bSrc + k0,            &Bs[tid * 8]);
    async16(bSrc + 64 * Kn + k0,  &Bs[2048 + tid * 8]);
    __builtin_amdgcn_s_waitcnt(0);
    __syncthreads();

    const int kq = (lane >> 4) * 8;
    const int rA = wr * 64 + (lane & 15);
    const int rB = wc * 64 + (lane & 15);
    bf16x8 af[4], bf[4];
#pragma unroll
    for (int i = 0; i < 4; i++) af[i] = *(const bf16x8*)&As[(rA + i * 16) * 32 + kq];
#pragma unroll
    for (int j = 0; j < 4; j++) bf[j] = *(const bf16x8*)&Bs[(rB + j * 16) * 32 + kq];
#pragma unroll
    for (int i = 0; i < 4; i++)
#pragma unroll
      for (int j = 0; j < 4; j++)
        acc[i][j] = __builtin_amdgcn_mfma_f32_16x16x32_bf16(af[i], bf[j], acc[i][j], 0, 0, 0);
    __syncthreads();
  }

  // epilogue: C/D layout col=lane&15 (N), row=(lane>>4)*4+r (M)
  const int region = blockIdx.y >> 2;       // 0=z(tanh) 1=f(sig) 2=o(sig), uniform per block
  const int rowB = wr * 64 + (lane >> 4) * 4;
  const int colB = wc * 64 + (lane & 15);
#pragma unroll
  for (int i = 0; i < 4; i++)
#pragma unroll
    for (int j = 0; j < 4; j++)
#pragma unroll
      for (int r = 0; r < 4; r++) {
        int mm = m0 + rowB + i * 16 + r;
        int nn = n0 + colB + j * 16;
        float g = acc[i][j][r] + bias[nn];
        float a = (region == 0) ? fast_tanh(g) : fast_sigmoid(g);
        gates[(size_t)mm * Nn + nn] = a;
      }
}

// ---- 4. per-chunk affine (a, bv): h_end = a*h_start + bv --------------------
__global__ __launch_bounds__(512) void scan_phaseA(const float* __restrict__ gates,
                                                   float* __restrict__ aArr,
                                                   float* __restrict__ bArr) {
  int u = threadIdx.x;
  int blk = blockIdx.x;                     // b*NC + c
  int b = blk >> 5, c = blk & (NC - 1);
  const float* gp = gates + (size_t)(b * Tn + c * CL) * Nn;
  float a = 1.0f, bv = 0.0f;
#pragma unroll 4
  for (int t = 0; t < CL; t++) {
    float z = gp[u];
    float f = gp[Un + u];
    a *= f;
    bv = f * bv + (1.0f - f) * z;
    gp += Nn;
  }
  aArr[(size_t)blk * Un + u] = a;
  bArr[(size_t)blk * Un + u] = bv;
}

// ---- 5. scan over chunks ----------------------------------------------------
__global__ __launch_bounds__(256) void scan_phaseB(const float* __restrict__ aArr,
                                                   const float* __restrict__ bArr,
                                                   const float* __restrict__ init,
                                                   float* __restrict__ hstart) {
  int idx = blockIdx.x * 256 + threadIdx.x; // 0..4095 = (b,u)
  int b = idx >> 9, u = idx & (Un - 1);
  float h = init[u];
  for (int c = 0; c < NC; c++) {
    size_t offc = (size_t)(b * NC + c) * Un + u;
    hstart[offc] = h;
    h = aArr[offc] * h + bArr[offc];
  }
}

// ---- 6. replay chunk with known h_start, apply output gate ------------------
__global__ __launch_bounds__(512) void scan_phaseC(const float* __restrict__ gates,
                                                   const float* __restrict__ hstart,
                                                   float* __restrict__ out) {
  int u = threadIdx.x;
  int blk = blockIdx.x;
  int b = blk >> 5, c = blk & (NC - 1);
  const float* gp = gates + (size_t)(b * Tn + c * CL) * Nn;
  float* op = out + (size_t)(b * Tn + c * CL) * Un;
  float h = hstart[(size_t)blk * Un + u];
#pragma unroll 4
  for (int t = 0; t < CL; t++) {
    float z = gp[u];
    float f = gp[Un + u];
    float o = gp[2 * Un + u];
    h = f * h + (1.0f - f) * z;
    op[u] = h * o;
    gp += Nn;
    op += Un;
  }
}

extern "C" void kernel_launch(void* const* d_in, const int* in_sizes, int n_in,
                              void* d_out, int out_size, void* d_ws, size_t ws_size,
                              hipStream_t stream) {
  const float* x    = (const float*)d_in[0];  // [8,2048,512]
  const float* kern = (const float*)d_in[1];  // [2,512,1536]
  const float* bias = (const float*)d_in[2];  // [1536]
  const float* init = (const float*)d_in[3];  // [1,512]
  float* out = (float*)d_out;                 // [8,2048,512]

  char* ws = (char*)d_ws;
  unsigned short* xb = (unsigned short*)ws;                      // 16,785,408 B
  size_t off = (size_t)Bn * (Tn + 1) * Cn * 2;
  unsigned short* kT = (unsigned short*)(ws + off);              // 3,145,728 B
  off += (size_t)Nn * Kn * 2;
  float* gates = (float*)(ws + off);                             // 100,663,296 B
  off += (size_t)Mn * Nn * 4;
  float* aArr = (float*)(ws + off);  off += (size_t)Bn * NC * Un * 4;
  float* bArr = (float*)(ws + off);  off += (size_t)Bn * NC * Un * 4;
  float* hstart = (float*)(ws + off);

  conv_x<<<(Bn * (Tn + 1) * Cn / 4) / 256, 256, 0, stream>>>(x, xb);
  conv_k<<<dim3(32, 48), 256, 0, stream>>>(kern, kT);
  gemm_gates<<<dim3(Mn / 128, Nn / 128), 256, 0, stream>>>(xb, kT, bias, gates);
  scan_phaseA<<<Bn * NC, 512, 0, stream>>>(gates, aArr, bArr);
  scan_phaseB<<<(Bn * Un) / 256, 256, 0, stream>>>(aArr, bArr, init, hstart);
  scan_phaseC<<<Bn * NC, 512, 0, stream>>>(gates, hstart, out);
}